// Round 1
// baseline (413.796 us; speedup 1.0000x reference)
//
#include <hip/hip_runtime.h>
#include <math.h>

#define EPS 1e-6f

// ---------------- degree count ----------------
__global__ void k_degrees(const int* __restrict__ ei, int E,
                          int* __restrict__ deg_src, int* __restrict__ deg_dst) {
    int e = blockIdx.x * blockDim.x + threadIdx.x;
    if (e < E) {
        atomicAdd(&deg_src[ei[e]], 1);
        atomicAdd(&deg_dst[ei[E + e]], 1);
    }
}

// ---------------- 1/sqrt(deg+eps) ----------------
__global__ void k_norms(const int* __restrict__ deg_src, const int* __restrict__ deg_dst,
                        float* __restrict__ norm_src, float* __restrict__ norm_dst, int N) {
    int n = blockIdx.x * blockDim.x + threadIdx.x;
    if (n < N) {
        norm_src[n] = 1.0f / sqrtf((float)deg_src[n] + EPS);
        norm_dst[n] = 1.0f / sqrtf((float)deg_dst[n] + EPS);
    }
}

// ---------------- exclusive scan of deg_dst (3-kernel scan) ----------------
__global__ void k_scan1(const int* __restrict__ deg, int N,
                        int* __restrict__ offsets, int* __restrict__ blockSums) {
    __shared__ int sm[256];
    int t = threadIdx.x;
    int i = blockIdx.x * 256 + t;
    int v = (i < N) ? deg[i] : 0;
    sm[t] = v;
    __syncthreads();
    for (int off = 1; off < 256; off <<= 1) {
        int add = (t >= off) ? sm[t - off] : 0;
        __syncthreads();
        sm[t] += add;
        __syncthreads();
    }
    if (i < N) offsets[i] = sm[t] - v;              // exclusive within block
    if (t == 255) blockSums[blockIdx.x] = sm[255];  // block total
}

__global__ void k_scan2(const int* __restrict__ blockSums, int* __restrict__ blockOffs,
                        int numBlocks) {
    __shared__ int sm[256];
    int t = threadIdx.x;
    int v = (t < numBlocks) ? blockSums[t] : 0;
    sm[t] = v;
    __syncthreads();
    for (int off = 1; off < 256; off <<= 1) {
        int add = (t >= off) ? sm[t - off] : 0;
        __syncthreads();
        sm[t] += add;
        __syncthreads();
    }
    if (t < numBlocks) blockOffs[t] = sm[t] - v;    // exclusive
}

__global__ void k_scan3(int* __restrict__ offsets, const int* __restrict__ blockOffs,
                        int N, int* __restrict__ cursor) {
    int i = blockIdx.x * 256 + threadIdx.x;
    if (i < N) {
        int o = offsets[i] + blockOffs[blockIdx.x];
        offsets[i] = o;
        cursor[i]  = o;
    }
}

// ---------------- CSR fill (grouped by dst, order within group arbitrary) ----------------
__global__ void k_fill(const int* __restrict__ ei, int E,
                       const float* __restrict__ norm_src, const float* __restrict__ norm_dst,
                       int* __restrict__ cursor,
                       int* __restrict__ edge_src, float* __restrict__ edge_coeff) {
    int e = blockIdx.x * blockDim.x + threadIdx.x;
    if (e < E) {
        int s = ei[e];
        int d = ei[E + e];
        float c = norm_src[s] * norm_dst[d];
        int p = atomicAdd(&cursor[d], 1);
        edge_src[p]   = s;
        edge_coeff[p] = c;
    }
}

// ---------------- y = x @ W  (fp32 vector ALU; 8 rows/block, 32 lanes/row, 4 cols/lane) ----
__launch_bounds__(256)
__global__ void k_gemm(const float* __restrict__ x, const float* __restrict__ w,
                       float* __restrict__ y, int N) {
    int t = threadIdx.x;
    int rowBase = blockIdx.x * 8;
    int r  = t >> 5;        // 0..7 local row
    int c4 = t & 31;        // 0..31 column group (4 floats)
    int row = rowBase + r;
    if (row >= N) return;
    const float4* w4   = (const float4*)w;                    // [128][32] float4
    const float*  xrow = x + (size_t)row * 128;
    float4 acc = make_float4(0.f, 0.f, 0.f, 0.f);
    #pragma unroll 8
    for (int k = 0; k < 128; ++k) {
        float  xv = xrow[k];                  // broadcast across 32 lanes (L1)
        float4 wv = w4[k * 32 + c4];          // coalesced 512B/row (L2, W=64KB)
        acc.x += xv * wv.x;
        acc.y += xv * wv.y;
        acc.z += xv * wv.z;
        acc.w += xv * wv.w;
    }
    ((float4*)(y + (size_t)row * 128))[c4] = acc;
}

// ---------------- gather: one wave per dst node, 64 lanes x float2 = 128 feats ----------
__launch_bounds__(256)
__global__ void k_gather(const int* __restrict__ offsets, const int* __restrict__ deg_dst,
                         const int* __restrict__ edge_src, const float* __restrict__ edge_coeff,
                         const float* __restrict__ y, const float* __restrict__ bias,
                         float* __restrict__ out, int N) {
    int gid  = blockIdx.x * blockDim.x + threadIdx.x;
    int node = gid >> 6;
    int lane = gid & 63;
    if (node >= N) return;
    int beg = offsets[node];
    int end = beg + deg_dst[node];
    const float2* y2 = (const float2*)y;
    float accx = 0.f, accy = 0.f;
    for (int j = beg; j < end; ++j) {
        int   s = edge_src[j];     // wave-uniform
        float c = edge_coeff[j];   // wave-uniform
        float2 v = y2[(size_t)s * 64 + lane];  // coalesced 512B per wave
        accx += c * v.x;
        accy += c * v.y;
    }
    float2 b = ((const float2*)bias)[lane];
    ((float2*)out)[(size_t)node * 64 + lane] = make_float2(accx + b.x, accy + b.y);
}

extern "C" void kernel_launch(void* const* d_in, const int* in_sizes, int n_in,
                              void* d_out, int out_size, void* d_ws, size_t ws_size,
                              hipStream_t stream) {
    const float* x    = (const float*)d_in[0];
    const int*   ei   = (const int*)d_in[1];
    const float* w    = (const float*)d_in[2];
    const float* bias = (const float*)d_in[3];
    float*       out  = (float*)d_out;

    const int C = 128;
    const int N = in_sizes[0] / C;   // 50000
    const int E = in_sizes[1] / 2;   // 800000

    // workspace carve-out (256B aligned chunks)
    char* ws = (char*)d_ws;
    size_t off = 0;
    auto alloc = [&](size_t bytes) -> void* {
        void* p = ws + off;
        off += (bytes + 255) & ~(size_t)255;
        return p;
    };
    int*   deg_src    = (int*)  alloc((size_t)N * 4);
    int*   deg_dst    = (int*)  alloc((size_t)N * 4);
    float* norm_src   = (float*)alloc((size_t)N * 4);
    float* norm_dst   = (float*)alloc((size_t)N * 4);
    int*   offsets    = (int*)  alloc((size_t)N * 4);
    int*   cursor     = (int*)  alloc((size_t)N * 4);
    int*   blockSums  = (int*)  alloc(256 * 4);
    int*   blockOffs  = (int*)  alloc(256 * 4);
    int*   edge_src   = (int*)  alloc((size_t)E * 4);
    float* edge_coeff = (float*)alloc((size_t)E * 4);
    float* y          = (float*)alloc((size_t)N * C * 4);
    (void)ws_size; // needs ~34MB

    const int TB = 256;
    hipMemsetAsync(deg_src, 0, (size_t)N * 4, stream);
    hipMemsetAsync(deg_dst, 0, (size_t)N * 4, stream);

    k_degrees<<<(E + TB - 1) / TB, TB, 0, stream>>>(ei, E, deg_src, deg_dst);
    k_norms  <<<(N + TB - 1) / TB, TB, 0, stream>>>(deg_src, deg_dst, norm_src, norm_dst, N);

    int nb = (N + 255) / 256;   // 196 for N=50000 (must be <= 256)
    k_scan1<<<nb, 256, 0, stream>>>(deg_dst, N, offsets, blockSums);
    k_scan2<<<1, 256, 0, stream>>>(blockSums, blockOffs, nb);
    k_scan3<<<nb, 256, 0, stream>>>(offsets, blockOffs, N, cursor);

    k_fill<<<(E + TB - 1) / TB, TB, 0, stream>>>(ei, E, norm_src, norm_dst,
                                                 cursor, edge_src, edge_coeff);

    k_gemm<<<(N + 7) / 8, 256, 0, stream>>>(x, w, y, N);

    long long gthreads = (long long)N * 64;
    k_gather<<<(int)((gthreads + TB - 1) / TB), TB, 0, stream>>>(
        offsets, deg_dst, edge_src, edge_coeff, y, bias, out, N);
}